// Round 1
// baseline (8050.247 us; speedup 1.0000x reference)
//
#include <hip/hip_runtime.h>
#include <hip/hip_bf16.h>

#define DEVFN __device__ __forceinline__

constexpr int B_   = 2;
constexpr int CIN  = 16;
constexpr int COUT = 16;
constexpr int T_   = 31;
constexpr int H_   = 128;
constexpr int W_   = 128;
constexpr int OC   = 6 * COUT;        // 96
constexpr int HW   = H_ * W_;         // 16384
constexpr int KVOL = CIN * 27;        // 432 weights per output channel

DEVFN float sigmoid_(float v) { return 1.f / (1.f + __expf(-v)); }
DEVFN float tanh_(float v)    { return 1.f - 2.f / (__expf(2.f * v) + 1.f); }

DEVFN float toF(float v) { return v; }
DEVFN float toF(__hip_bfloat16 v) { return __bfloat162float(v); }
DEVFN void storeG(float& d, float v) { d = v; }
DEVFN void storeG(__hip_bfloat16& d, float v) { d = __float2bfloat16(v); }

// ---------------------------------------------------------------------------
// Kernel 1: direct 3x3x3 conv (CIN=16) + bias + activation, one thread per
// output gate element. Gate planes stored [g][b][c][t][h][w], g in 0..5:
//   0=Wx(tanh) 1=ft(sig) 2=ft2(sig) 3=rt(sig) 4=rt2(sig) 5=X(tanh)
// blockIdx: x = spatial chunk (64), y = oc (96, wave-uniform weights),
//           z = b*T + t (62). x-fastest dispatch => all oc-blocks for one
//           (b,t) reuse the ~3 MB x slab in per-XCD L2.
// ---------------------------------------------------------------------------
template <typename GT>
__global__ __launch_bounds__(256) void conv_gates_kernel(
    const float* __restrict__ x, const float* __restrict__ cw,
    const float* __restrict__ cb, GT* __restrict__ gates) {
  const int sp = blockIdx.x * 256 + threadIdx.x;  // 0..16383
  const int oc = blockIdx.y;                      // 0..95
  const int bt = blockIdx.z;                      // 0..61
  const int b  = bt / T_;
  const int t  = bt - b * T_;
  const int h  = sp >> 7;
  const int wc = sp & (W_ - 1);

  __shared__ float wsh[KVOL];
  for (int i = threadIdx.x; i < KVOL; i += 256) wsh[i] = cw[oc * KVOL + i];
  __syncthreads();

  float acc = cb[oc];
  const float* xb = x + b * (CIN * T_ * HW);
  for (int ci = 0; ci < CIN; ++ci) {
    const float* xc = xb + ci * (T_ * HW);
#pragma unroll
    for (int kd = 0; kd < 3; ++kd) {
      const int tt = t + kd - 1;
      if ((unsigned)tt >= (unsigned)T_) continue;
      const float* xt = xc + tt * HW;
#pragma unroll
      for (int kh = 0; kh < 3; ++kh) {
        const int hh = h + kh - 1;
        if ((unsigned)hh >= (unsigned)H_) continue;
        const float* xr = xt + hh * W_;
        const float* wr = &wsh[(ci * 3 + kd) * 9 + kh * 3];
        if (wc > 0)      acc += wr[0] * xr[wc - 1];
        acc += wr[1] * xr[wc];
        if (wc < W_ - 1) acc += wr[2] * xr[wc + 1];
      }
    }
  }

  const int g = oc >> 4, c = oc & 15;
  const float av = (g == 0 || g == 5) ? tanh_(acc) : sigmoid_(acc);
  const int off = (((g * B_ + b) * COUT + c) * T_ + t) * HW + sp;
  storeG(gates[off], av);
}

// ---------------------------------------------------------------------------
// Kernel 2: bidirectional SRU scan. One thread per (b,c,h,w); T fully
// unrolled; wx/x/htl held in registers so every gate plane is read once.
// ---------------------------------------------------------------------------
template <typename GT>
__global__ __launch_bounds__(256) void sru_scan_kernel(
    const GT* __restrict__ g, float* __restrict__ out) {
  const int idx  = blockIdx.x * 256 + threadIdx.x;  // 0..524287
  const int sp   = idx & (HW - 1);
  const int bc   = idx >> 14;                       // b*16 + c
  const int base = bc * (T_ * HW) + sp;
  const int P    = B_ * COUT * T_ * HW;

  const GT* gWx = g + 0 * P + base;
  const GT* gF  = g + 1 * P + base;
  const GT* gF2 = g + 2 * P + base;
  const GT* gR  = g + 3 * P + base;
  const GT* gR2 = g + 4 * P + base;
  const GT* gX  = g + 5 * P + base;

  float wxs[T_], xs[T_], htl[T_];
  float C = 0.f;
#pragma unroll
  for (int t = 0; t < T_; ++t) {
    const float wx = toF(gWx[t * HW]);
    const float f  = toF(gF[t * HW]);
    const float r  = toF(gR[t * HW]);
    const float xv = toF(gX[t * HW]);
    wxs[t] = wx;
    xs[t]  = xv;
    C = (t == 0) ? (1.f - f) : (f * C + (1.f - f) * wx);
    htl[t] = r * C + (1.f - r) * xv;
  }
  float C2 = 0.f;
#pragma unroll
  for (int t = T_ - 1; t >= 0; --t) {
    const float f2 = toF(gF2[t * HW]);
    const float r2 = toF(gR2[t * HW]);
    C2 = (t == T_ - 1) ? (1.f - f2) : (f2 * C2 + (1.f - f2) * wxs[t]);
    const float htr = r2 * C2 + (1.f - r2) * xs[t];
    out[base + t * HW] = htl[t] + htr;
  }
}

// ---------------------------------------------------------------------------
// Fallback (only if ws too small): fused conv+scan, recomputes conv per
// direction. dir=0 writes htl, dir=1 adds htr.
// ---------------------------------------------------------------------------
__global__ __launch_bounds__(256) void sru_fused_dir(
    const float* __restrict__ x, const float* __restrict__ cw,
    const float* __restrict__ cb, float* __restrict__ out, int dir) {
  const int sp = blockIdx.x * 256 + threadIdx.x;
  const int bc = blockIdx.y;  // b*16 + c
  const int b  = bc >> 4, c = bc & 15;
  const int h  = sp >> 7, wc = sp & (W_ - 1);

  const int ocWx = c;
  const int ocF  = dir ? 32 + c : 16 + c;
  const int ocR  = dir ? 64 + c : 48 + c;
  const int ocX  = 80 + c;
  const float* w0 = cw + ocWx * KVOL;
  const float* w1 = cw + ocF * KVOL;
  const float* w2 = cw + ocR * KVOL;
  const float* w3 = cw + ocX * KVOL;

  const float* xb = x + b * (CIN * T_ * HW);
  const int obase = bc * (T_ * HW) + sp;
  float C = 0.f;
  for (int i = 0; i < T_; ++i) {
    const int t = dir ? (T_ - 1 - i) : i;
    float a0 = cb[ocWx], a1 = cb[ocF], a2 = cb[ocR], a3 = cb[ocX];
    for (int ci = 0; ci < CIN; ++ci) {
      const float* xc = xb + ci * (T_ * HW);
#pragma unroll
      for (int kd = 0; kd < 3; ++kd) {
        const int tt = t + kd - 1;
        if ((unsigned)tt >= (unsigned)T_) continue;
        const float* xt = xc + tt * HW;
#pragma unroll
        for (int kh = 0; kh < 3; ++kh) {
          const int hh = h + kh - 1;
          if ((unsigned)hh >= (unsigned)H_) continue;
          const float* xr = xt + hh * W_;
          const int wi = (ci * 3 + kd) * 9 + kh * 3;
#pragma unroll
          for (int kw = 0; kw < 3; ++kw) {
            const int ww = wc + kw - 1;
            if ((unsigned)ww >= (unsigned)W_) continue;
            const float xv = xr[ww];
            a0 += w0[wi + kw] * xv;
            a1 += w1[wi + kw] * xv;
            a2 += w2[wi + kw] * xv;
            a3 += w3[wi + kw] * xv;
          }
        }
      }
    }
    const float wx = tanh_(a0), f = sigmoid_(a1), r = sigmoid_(a2),
                xv = tanh_(a3);
    C = (i == 0) ? (1.f - f) : (f * C + (1.f - f) * wx);
    const float hcur = r * C + (1.f - r) * xv;
    if (dir) out[obase + t * HW] += hcur;
    else     out[obase + t * HW] = hcur;
  }
}

extern "C" void kernel_launch(void* const* d_in, const int* in_sizes, int n_in,
                              void* d_out, int out_size, void* d_ws,
                              size_t ws_size, hipStream_t stream) {
  (void)in_sizes; (void)n_in; (void)out_size;
  const float* x  = (const float*)d_in[0];
  const float* cw = (const float*)d_in[1];
  const float* cb = (const float*)d_in[2];
  float* out = (float*)d_out;

  const size_t planeElems = (size_t)B_ * COUT * T_ * HW;  // 16,252,928
  const size_t need_f32   = 6 * planeElems * sizeof(float);
  const size_t need_bf16  = 6 * planeElems * sizeof(__hip_bfloat16);

  const dim3 gconv(HW / 256, OC, B_ * T_);
  const int scanBlocks = (B_ * COUT * HW) / 256;  // 2048

  if (ws_size >= need_f32) {
    float* gates = (float*)d_ws;
    conv_gates_kernel<float><<<gconv, 256, 0, stream>>>(x, cw, cb, gates);
    sru_scan_kernel<float><<<scanBlocks, 256, 0, stream>>>(gates, out);
  } else if (ws_size >= need_bf16) {
    __hip_bfloat16* gates = (__hip_bfloat16*)d_ws;
    conv_gates_kernel<__hip_bfloat16><<<gconv, 256, 0, stream>>>(x, cw, cb,
                                                                 gates);
    sru_scan_kernel<__hip_bfloat16><<<scanBlocks, 256, 0, stream>>>(gates,
                                                                    out);
  } else {
    const dim3 gf(HW / 256, B_ * COUT);
    sru_fused_dir<<<gf, 256, 0, stream>>>(x, cw, cb, out, 0);
    sru_fused_dir<<<gf, 256, 0, stream>>>(x, cw, cb, out, 1);
  }
}

// Round 2
// 521.679 us; speedup vs baseline: 15.4314x; 15.4314x over previous
//
#include <hip/hip_runtime.h>

#define DEVFN __device__ __forceinline__

typedef __attribute__((ext_vector_type(8))) short short8;
typedef __attribute__((ext_vector_type(4))) float floatx4;
typedef unsigned short u16;
typedef unsigned int u32;

constexpr int B_   = 2;
constexpr int CIN  = 16;
constexpr int COUT = 16;
constexpr int T_   = 31;
constexpr int H_   = 128;
constexpr int W_   = 128;
constexpr int OC   = 6 * COUT;   // 96
constexpr int HW   = H_ * W_;    // 16384
constexpr int KVOL = CIN * 27;   // 432
constexpr int KP   = 448;        // K padded to 14 * 32

// padded x layout [b][TP][HP][WP][16ci], bf16 hi/lo
constexpr int TP = T_ + 2;       // 33
constexpr int HP = H_ + 2;       // 130
constexpr int WP = W_ + 2;       // 130
constexpr int Sh = WP * 16;      // 2080 elems per hh step
constexpr int St = HP * Sh;      // 270400 elems per tt step
constexpr int NPAD = B_ * TP * HP * WP;  // 1,115,400 positions

DEVFN float sigmoid_(float v) { return 1.f / (1.f + __expf(-v)); }
DEVFN float tanh_(float v)    { return 1.f - 2.f / (__expf(2.f * v) + 1.f); }

DEVFN u16 f2bf(float v) {  // RNE float->bf16 (raw bits)
  u32 u = __float_as_uint(v);
  return (u16)((u + 0x7fffu + ((u >> 16) & 1u)) >> 16);
}
DEVFN float bf2f(u16 h) { return __uint_as_float(((u32)h) << 16); }

DEVFN float toF(float v) { return v; }
DEVFN float toF(u16 v) { return bf2f(v); }
DEVFN void storeG(float& d, float v) { d = v; }
DEVFN void storeG(u16& d, float v) { d = f2bf(v); }

// delta (in elems) into padded-x for kernel offset off = kd*9+kh*3+kw;
// off==27 (the K pad) clamps to 26 — A weights there are zero.
DEVFN constexpr int dOff(int off) {
  const int o = (off < 27) ? off : 26;
  return (o / 9) * St + ((o % 9) / 3) * Sh + (o % 3) * 16;
}

// ---------------------------------------------------------------------------
// Pre-kernel 1: split fp32 x into bf16 hi + lo, transposed to ci-innermost,
// zero-padded borders (so the conv kernel needs no boundary logic).
// ---------------------------------------------------------------------------
__global__ __launch_bounds__(256) void split_pad_x(
    const float* __restrict__ x, u16* __restrict__ xhi, u16* __restrict__ xlo) {
  const int idx = blockIdx.x * 256 + threadIdx.x;
  if (idx >= NPAD) return;
  int r = idx;
  const int ww = r % WP; r /= WP;
  const int hh = r % HP; r /= HP;
  const int tt = r % TP; const int b = r / TP;
  const bool in_ = (tt >= 1) & (tt <= T_) & (hh >= 1) & (hh <= H_) &
                   (ww >= 1) & (ww <= W_);
  const int ts = in_ ? tt - 1 : 0, hs = in_ ? hh - 1 : 0, ws = in_ ? ww - 1 : 0;
  const float* xp = x + ((size_t)b * CIN * T_ + ts) * HW + hs * W_ + ws;
  u32 ph[8], pl[8];
#pragma unroll
  for (int ci = 0; ci < 16; ++ci) {
    const float v = in_ ? xp[ci * (T_ * HW)] : 0.f;
    const u16 hu = f2bf(v);
    const u16 lu = f2bf(v - bf2f(hu));
    if (ci & 1) { ph[ci >> 1] |= ((u32)hu) << 16; pl[ci >> 1] |= ((u32)lu) << 16; }
    else        { ph[ci >> 1] = hu;               pl[ci >> 1] = lu; }
  }
  uint4* dh = (uint4*)(xhi + (size_t)idx * 16);
  uint4* dl = (uint4*)(xlo + (size_t)idx * 16);
  dh[0] = make_uint4(ph[0], ph[1], ph[2], ph[3]);
  dh[1] = make_uint4(ph[4], ph[5], ph[6], ph[7]);
  dl[0] = make_uint4(pl[0], pl[1], pl[2], pl[3]);
  dl[1] = make_uint4(pl[4], pl[5], pl[6], pl[7]);
}

// ---------------------------------------------------------------------------
// Pre-kernel 2: weights [oc][ci][27] fp32 -> [oc][off*16+ci] bf16, K padded.
// ---------------------------------------------------------------------------
__global__ __launch_bounds__(256) void reorder_w(const float* __restrict__ cw,
                                                 u16* __restrict__ wr) {
  const int idx = blockIdx.x * 256 + threadIdx.x;
  if (idx >= OC * KP) return;
  const int oc = idx / KP, kk = idx - oc * KP;
  const int off = kk >> 4, ci = kk & 15;
  const float v = (off < 27) ? cw[oc * KVOL + ci * 27 + off] : 0.f;
  wr[idx] = f2bf(v);
}

// ---------------------------------------------------------------------------
// Main conv: implicit GEMM via mfma_f32_16x16x32_bf16.
// A = weights [M=96][K=448] (bf16), B = padded x patches (hi+lo bf16),
// acc fp32. Wave computes 96 oc x 32 positions; block = 4 waves = one
// (b,t,h) row of 128 w. Layouts (HW-verified per guide §3):
//   A: m=lane&15, k=quad*8+j ; B: n=lane&15, k=quad*8+j ;
//   D: col(n)=lane&15, row(m)=quad*4+reg.
// k-order = off*16+ci so each fragment is one contiguous 16 B load.
// ---------------------------------------------------------------------------
template <typename GT>
__global__ __launch_bounds__(256) void conv_mfma(
    const u16* __restrict__ xhi, const u16* __restrict__ xlo,
    const u16* __restrict__ wr, const float* __restrict__ cb,
    GT* __restrict__ gates) {
  const int lane = threadIdx.x & 63, wv = threadIdx.x >> 6;
  const int n = lane & 15, quad = lane >> 4;
  const int qhalf = quad >> 1, cihalf = quad & 1;
  const int h = blockIdx.x, bt = blockIdx.y;
  const int b = bt / T_, t = bt - b * T_;
  const int wpos = wv * 32 + n;  // first n-tile position; second = +16
  // padded-x base at (kd,kh,kw)=(0,0,0): tt=t, hh=h, ww=wpos
  const int base0 = (((b * TP + t) * HP + h) * WP + wpos) * 16 + cihalf * 8;
  const int base1 = base0 + 16 * 16;

  floatx4 acc[6][2];
#pragma unroll
  for (int m = 0; m < 6; ++m)
#pragma unroll
    for (int j = 0; j < 2; ++j) acc[m][j] = (floatx4)(0.f);

#pragma unroll
  for (int s = 0; s < 14; ++s) {
    const int d = qhalf ? dOff(2 * s + 1) : dOff(2 * s);
    const short8 bh0 = *(const short8*)(xhi + base0 + d);
    const short8 bl0 = *(const short8*)(xlo + base0 + d);
    const short8 bh1 = *(const short8*)(xhi + base1 + d);
    const short8 bl1 = *(const short8*)(xlo + base1 + d);
#pragma unroll
    for (int m = 0; m < 6; ++m) {
      const short8 a = *(const short8*)(wr + (m * 16 + n) * KP + s * 32 + quad * 8);
      acc[m][0] = __builtin_amdgcn_mfma_f32_16x16x32_bf16(a, bh0, acc[m][0], 0, 0, 0);
      acc[m][0] = __builtin_amdgcn_mfma_f32_16x16x32_bf16(a, bl0, acc[m][0], 0, 0, 0);
      acc[m][1] = __builtin_amdgcn_mfma_f32_16x16x32_bf16(a, bh1, acc[m][1], 0, 0, 0);
      acc[m][1] = __builtin_amdgcn_mfma_f32_16x16x32_bf16(a, bl1, acc[m][1], 0, 0, 0);
    }
  }

  // epilogue: bias + activation + store. gate g == m-tile (uniform per m).
#pragma unroll
  for (int m = 0; m < 6; ++m) {
    const bool isTanh = (m == 0) || (m == 5);
#pragma unroll
    for (int r = 0; r < 4; ++r) {
      const int c = quad * 4 + r;
      const float bias = cb[m * 16 + c];
      const int obase = (((m * B_ + b) * COUT + c) * T_ + t) * HW + h * W_;
      float v0 = acc[m][0][r] + bias;
      float v1 = acc[m][1][r] + bias;
      v0 = isTanh ? tanh_(v0) : sigmoid_(v0);
      v1 = isTanh ? tanh_(v1) : sigmoid_(v1);
      storeG(gates[obase + wpos], v0);
      storeG(gates[obase + wpos + 16], v1);
    }
  }
}

// ---------------------------------------------------------------------------
// Bidirectional SRU scan (unchanged from R1, GT = float | bf16-raw-u16).
// ---------------------------------------------------------------------------
template <typename GT>
__global__ __launch_bounds__(256) void sru_scan_kernel(
    const GT* __restrict__ g, float* __restrict__ out) {
  const int idx  = blockIdx.x * 256 + threadIdx.x;
  const int sp   = idx & (HW - 1);
  const int bc   = idx >> 14;
  const int base = bc * (T_ * HW) + sp;
  const int P    = B_ * COUT * T_ * HW;

  const GT* gWx = g + 0 * P + base;
  const GT* gF  = g + 1 * P + base;
  const GT* gF2 = g + 2 * P + base;
  const GT* gR  = g + 3 * P + base;
  const GT* gR2 = g + 4 * P + base;
  const GT* gX  = g + 5 * P + base;

  float wxs[T_], xs[T_], htl[T_];
  float C = 0.f;
#pragma unroll
  for (int t = 0; t < T_; ++t) {
    const float wx = toF(gWx[t * HW]);
    const float f  = toF(gF[t * HW]);
    const float r  = toF(gR[t * HW]);
    const float xv = toF(gX[t * HW]);
    wxs[t] = wx;
    xs[t]  = xv;
    C = (t == 0) ? (1.f - f) : (f * C + (1.f - f) * wx);
    htl[t] = r * C + (1.f - r) * xv;
  }
  float C2 = 0.f;
#pragma unroll
  for (int t = T_ - 1; t >= 0; --t) {
    const float f2 = toF(gF2[t * HW]);
    const float r2 = toF(gR2[t * HW]);
    C2 = (t == T_ - 1) ? (1.f - f2) : (f2 * C2 + (1.f - f2) * wxs[t]);
    const float htr = r2 * C2 + (1.f - r2) * xs[t];
    out[base + t * HW] = htl[t] + htr;
  }
}

// ---------------------------------------------------------------------------
// Fallback direct conv (R1 version) — only if ws too small for MFMA path.
// ---------------------------------------------------------------------------
template <typename GT>
__global__ __launch_bounds__(256) void conv_gates_kernel(
    const float* __restrict__ x, const float* __restrict__ cw,
    const float* __restrict__ cb, GT* __restrict__ gates) {
  const int sp = blockIdx.x * 256 + threadIdx.x;
  const int oc = blockIdx.y;
  const int bt = blockIdx.z;
  const int b  = bt / T_;
  const int t  = bt - b * T_;
  const int h  = sp >> 7;
  const int wc = sp & (W_ - 1);

  __shared__ float wsh[KVOL];
  for (int i = threadIdx.x; i < KVOL; i += 256) wsh[i] = cw[oc * KVOL + i];
  __syncthreads();

  float acc = cb[oc];
  const float* xb = x + b * (CIN * T_ * HW);
  for (int ci = 0; ci < CIN; ++ci) {
    const float* xc = xb + ci * (T_ * HW);
#pragma unroll
    for (int kd = 0; kd < 3; ++kd) {
      const int tt = t + kd - 1;
      if ((unsigned)tt >= (unsigned)T_) continue;
      const float* xt = xc + tt * HW;
#pragma unroll
      for (int kh = 0; kh < 3; ++kh) {
        const int hh = h + kh - 1;
        if ((unsigned)hh >= (unsigned)H_) continue;
        const float* xr = xt + hh * W_;
        const float* wrp = &wsh[(ci * 3 + kd) * 9 + kh * 3];
        if (wc > 0)      acc += wrp[0] * xr[wc - 1];
        acc += wrp[1] * xr[wc];
        if (wc < W_ - 1) acc += wrp[2] * xr[wc + 1];
      }
    }
  }
  const int g = oc >> 4, c = oc & 15;
  const float av = (g == 0 || g == 5) ? tanh_(acc) : sigmoid_(acc);
  const int off = (((g * B_ + b) * COUT + c) * T_ + t) * HW + sp;
  storeG(gates[off], av);
}

extern "C" void kernel_launch(void* const* d_in, const int* in_sizes, int n_in,
                              void* d_out, int out_size, void* d_ws,
                              size_t ws_size, hipStream_t stream) {
  (void)in_sizes; (void)n_in; (void)out_size;
  const float* x  = (const float*)d_in[0];
  const float* cw = (const float*)d_in[1];
  const float* cb = (const float*)d_in[2];
  float* out = (float*)d_out;

  const size_t planeElems = (size_t)B_ * COUT * T_ * HW;        // 16,252,928
  const size_t szGatesF = 6 * planeElems * sizeof(float);       // 390,070,272
  const size_t szGatesH = 6 * planeElems * sizeof(u16);         // 195,035,136
  const size_t szX      = (size_t)NPAD * 16 * sizeof(u16);      // 35,692,800
  const size_t szW      = (size_t)OC * KP * sizeof(u16);        // 86,016

  const int splitBlocks = (NPAD + 255) / 256;
  const int wBlocks     = (OC * KP + 255) / 256;
  const dim3 gconv(H_, B_ * T_);          // 128 x 62
  const int scanBlocks = (B_ * COUT * HW) / 256;  // 2048

  char* p = (char*)d_ws;
  if (ws_size >= szGatesF + 2 * szX + szW) {
    float* gates = (float*)p;
    u16* xhi = (u16*)(p + szGatesF);
    u16* xlo = (u16*)(p + szGatesF + szX);
    u16* wr  = (u16*)(p + szGatesF + 2 * szX);
    split_pad_x<<<splitBlocks, 256, 0, stream>>>(x, xhi, xlo);
    reorder_w<<<wBlocks, 256, 0, stream>>>(cw, wr);
    conv_mfma<float><<<gconv, 256, 0, stream>>>(xhi, xlo, wr, cb, gates);
    sru_scan_kernel<float><<<scanBlocks, 256, 0, stream>>>(gates, out);
  } else if (ws_size >= szGatesH + 2 * szX + szW) {
    u16* gates = (u16*)p;
    u16* xhi = (u16*)(p + szGatesH);
    u16* xlo = (u16*)(p + szGatesH + szX);
    u16* wr  = (u16*)(p + szGatesH + 2 * szX);
    split_pad_x<<<splitBlocks, 256, 0, stream>>>(x, xhi, xlo);
    reorder_w<<<wBlocks, 256, 0, stream>>>(cw, wr);
    conv_mfma<u16><<<gconv, 256, 0, stream>>>(xhi, xlo, wr, cb, gates);
    sru_scan_kernel<u16><<<scanBlocks, 256, 0, stream>>>(gates, out);
  } else if (ws_size >= szGatesF) {
    float* gates = (float*)p;
    const dim3 gdir(HW / 256, OC, B_ * T_);
    conv_gates_kernel<float><<<gdir, 256, 0, stream>>>(x, cw, cb, gates);
    sru_scan_kernel<float><<<scanBlocks, 256, 0, stream>>>(gates, out);
  } else {
    u16* gates = (u16*)p;
    const dim3 gdir(HW / 256, OC, B_ * T_);
    conv_gates_kernel<u16><<<gdir, 256, 0, stream>>>(x, cw, cb, gates);
    sru_scan_kernel<u16><<<scanBlocks, 256, 0, stream>>>(gates, out);
  }
}

// Round 3
// 350.379 us; speedup vs baseline: 22.9758x; 1.4889x over previous
//
#include <hip/hip_runtime.h>

#define DEVFN __device__ __forceinline__

typedef __attribute__((ext_vector_type(8))) short short8;
typedef __attribute__((ext_vector_type(4))) float floatx4;
typedef unsigned short u16;
typedef unsigned int u32;

constexpr int B_   = 2;
constexpr int CIN  = 16;
constexpr int COUT = 16;
constexpr int T_   = 31;
constexpr int H_   = 128;
constexpr int W_   = 128;
constexpr int OC   = 6 * COUT;   // 96
constexpr int HW   = H_ * W_;    // 16384
constexpr int KVOL = CIN * 27;   // 432
constexpr int KP   = 448;        // K padded to 14 * 32

// padded x layout [b][TP][HP][WP][16ci], bf16 hi/lo
constexpr int TP = T_ + 2;       // 33
constexpr int HP = H_ + 2;       // 130
constexpr int WP = W_ + 2;       // 130
constexpr int Sh = WP * 16;      // 2080 elems per hh step
constexpr int St = HP * Sh;      // 270400 elems per tt step
constexpr int NPAD = B_ * TP * HP * WP;  // 1,115,400 positions

// A-in-LDS: one phase = 7 k-steps, layout [sl(7)][m(6)][quad(4)][n(16)][j(8)]
constexpr int APH = 7 * 6 * 4 * 16 * 8;  // 21504 elems = 43008 B per phase

DEVFN float sigmoid_(float v) { return 1.f / (1.f + __expf(-v)); }
DEVFN float tanh_(float v)    { return 1.f - 2.f / (__expf(2.f * v) + 1.f); }

DEVFN u16 f2bf(float v) {  // RNE float->bf16 (raw bits)
  u32 u = __float_as_uint(v);
  return (u16)((u + 0x7fffu + ((u >> 16) & 1u)) >> 16);
}
DEVFN float bf2f(u16 h) { return __uint_as_float(((u32)h) << 16); }

DEVFN float toF(float v) { return v; }
DEVFN float toF(u16 v) { return bf2f(v); }
DEVFN void storeG(float& d, float v) { d = v; }
DEVFN void storeG(u16& d, float v) { d = f2bf(v); }

// delta (in elems) into padded-x for kernel offset off = kd*9+kh*3+kw;
// off==27 (the K pad) clamps to 26 — A weights there are zero.
DEVFN constexpr int dOff(int off) {
  const int o = (off < 27) ? off : 26;
  return (o / 9) * St + ((o % 9) / 3) * Sh + (o % 3) * 16;
}

// ---------------------------------------------------------------------------
// Pre-kernel 1: split fp32 x into bf16 hi + lo, transposed to ci-innermost,
// zero-padded borders.
// ---------------------------------------------------------------------------
__global__ __launch_bounds__(256) void split_pad_x(
    const float* __restrict__ x, u16* __restrict__ xhi, u16* __restrict__ xlo) {
  const int idx = blockIdx.x * 256 + threadIdx.x;
  if (idx >= NPAD) return;
  int r = idx;
  const int ww = r % WP; r /= WP;
  const int hh = r % HP; r /= HP;
  const int tt = r % TP; const int b = r / TP;
  const bool in_ = (tt >= 1) & (tt <= T_) & (hh >= 1) & (hh <= H_) &
                   (ww >= 1) & (ww <= W_);
  const int ts = in_ ? tt - 1 : 0, hs = in_ ? hh - 1 : 0, ws = in_ ? ww - 1 : 0;
  const float* xp = x + ((size_t)b * CIN * T_ + ts) * HW + hs * W_ + ws;
  u32 ph[8], pl[8];
#pragma unroll
  for (int ci = 0; ci < 16; ++ci) {
    const float v = in_ ? xp[ci * (T_ * HW)] : 0.f;
    const u16 hu = f2bf(v);
    const u16 lu = f2bf(v - bf2f(hu));
    if (ci & 1) { ph[ci >> 1] |= ((u32)hu) << 16; pl[ci >> 1] |= ((u32)lu) << 16; }
    else        { ph[ci >> 1] = hu;               pl[ci >> 1] = lu; }
  }
  uint4* dh = (uint4*)(xhi + (size_t)idx * 16);
  uint4* dl = (uint4*)(xlo + (size_t)idx * 16);
  dh[0] = make_uint4(ph[0], ph[1], ph[2], ph[3]);
  dh[1] = make_uint4(ph[4], ph[5], ph[6], ph[7]);
  dl[0] = make_uint4(pl[0], pl[1], pl[2], pl[3]);
  dl[1] = make_uint4(pl[4], pl[5], pl[6], pl[7]);
}

// ---------------------------------------------------------------------------
// Pre-kernel 2: weights [oc][ci][27] fp32 -> LDS-ready bf16 layout
// [s(14)][m(6)][quad(4)][n(16)][j(8)], oc = m*16+n, k = s*32+quad*8+j.
// This makes the conv's A fragment a conflict-free ds_read_b128 at
// wave-uniform base + lane*16.
// ---------------------------------------------------------------------------
__global__ __launch_bounds__(256) void reorder_w(const float* __restrict__ cw,
                                                 u16* __restrict__ wr) {
  const int idx = blockIdx.x * 256 + threadIdx.x;
  if (idx >= OC * KP) return;
  const int j    = idx & 7;
  const int n    = (idx >> 3) & 15;
  const int quad = (idx >> 7) & 3;
  const int m    = (idx >> 9) % 6;
  const int s    = idx / 3072;
  const int oc   = m * 16 + n;
  const int k    = s * 32 + quad * 8 + j;
  const int off  = k >> 4, ci = k & 15;
  const float v  = (off < 27) ? cw[oc * KVOL + ci * 27 + off] : 0.f;
  wr[idx] = f2bf(v);
}

// ---------------------------------------------------------------------------
// One k-phase (7 steps), PH compile-time so dOff folds to immediates.
// ---------------------------------------------------------------------------
template <int PH>
DEVFN void kphase(const u16* __restrict__ xhi, const u16* __restrict__ xlo,
                  const u16* As, int pbase, int n, int quad, int qhalf,
                  floatx4 (&acc)[6][4]) {
#pragma unroll
  for (int sl = 0; sl < 7; ++sl) {
    const int s = PH * 7 + sl;
    const int d = qhalf ? dOff(2 * s + 1) : dOff(2 * s);
    short8 bh[4], bl[4];
#pragma unroll
    for (int j = 0; j < 4; ++j) {
      bh[j] = *(const short8*)(xhi + pbase + j * 256 + d);
      bl[j] = *(const short8*)(xlo + pbase + j * 256 + d);
    }
#pragma unroll
    for (int m = 0; m < 6; ++m) {
      const short8 a = *(const short8*)(As + (sl * 6 + m) * 512 + quad * 128 + n * 8);
#pragma unroll
      for (int j = 0; j < 4; ++j) {
        acc[m][j] = __builtin_amdgcn_mfma_f32_16x16x32_bf16(a, bh[j], acc[m][j], 0, 0, 0);
        acc[m][j] = __builtin_amdgcn_mfma_f32_16x16x32_bf16(a, bl[j], acc[m][j], 0, 0, 0);
      }
    }
  }
}

// ---------------------------------------------------------------------------
// Main conv: implicit GEMM, A(weights 96x448) in LDS, B(x patches) from
// global. Block = 4 waves; wave = 64 positions (4 n-tiles); block = 2 h rows.
// Layouts (verified in R2): A rows m=lane&15 (=oc), B cols n=lane&15 (=pos),
// D col=lane&15 (=pos), row=quad*4+reg (=oc).
// ---------------------------------------------------------------------------
template <typename GT>
__global__ __launch_bounds__(256) void conv_mfma(
    const u16* __restrict__ xhi, const u16* __restrict__ xlo,
    const u16* __restrict__ wr, const float* __restrict__ cb,
    GT* __restrict__ gates) {
  const int lane = threadIdx.x & 63, wv = threadIdx.x >> 6;
  const int n = lane & 15, quad = lane >> 4;
  const int qhalf = quad >> 1, cihalf = quad & 1;
  const int h = blockIdx.x * 2 + (wv >> 1);
  const int wbase = (wv & 1) * 64;            // wave's first position
  const int bt = blockIdx.y;
  const int b = bt / T_, t = bt - b * T_;

  __shared__ u16 As[APH];  // 43008 B

  // padded-x base at (kd,kh,kw)=(0,0,0) for this lane's n-tile 0 position
  const int pbase = (((b * TP + t) * HP + h) * WP + wbase + n) * 16 + cihalf * 8;

  floatx4 acc[6][4];
#pragma unroll
  for (int m = 0; m < 6; ++m)
#pragma unroll
    for (int j = 0; j < 4; ++j) acc[m][j] = (floatx4)(0.f);

  // phase 0: stage A[s=0..6], compute
  for (int i = threadIdx.x; i < APH / 8; i += 256)
    ((uint4*)As)[i] = ((const uint4*)wr)[i];
  __syncthreads();
  kphase<0>(xhi, xlo, As, pbase, n, quad, qhalf, acc);

  // phase 1: restage A[s=7..13], compute
  __syncthreads();
  for (int i = threadIdx.x; i < APH / 8; i += 256)
    ((uint4*)As)[i] = ((const uint4*)(wr + APH))[i];
  __syncthreads();
  kphase<1>(xhi, xlo, As, pbase, n, quad, qhalf, acc);

  // epilogue: bias + activation + store (gate g == m-tile)
#pragma unroll
  for (int m = 0; m < 6; ++m) {
    const bool isTanh = (m == 0) || (m == 5);
#pragma unroll
    for (int r = 0; r < 4; ++r) {
      const int c = quad * 4 + r;
      const float bias = cb[m * 16 + c];
      const int obase =
          (((m * B_ + b) * COUT + c) * T_ + t) * HW + h * W_ + wbase + n;
#pragma unroll
      for (int j = 0; j < 4; ++j) {
        float v = acc[m][j][r] + bias;
        v = isTanh ? tanh_(v) : sigmoid_(v);
        storeG(gates[obase + j * 16], v);
      }
    }
  }
}

// ---------------------------------------------------------------------------
// Bidirectional SRU scan (unchanged).
// ---------------------------------------------------------------------------
template <typename GT>
__global__ __launch_bounds__(256) void sru_scan_kernel(
    const GT* __restrict__ g, float* __restrict__ out) {
  const int idx  = blockIdx.x * 256 + threadIdx.x;
  const int sp   = idx & (HW - 1);
  const int bc   = idx >> 14;
  const int base = bc * (T_ * HW) + sp;
  const int P    = B_ * COUT * T_ * HW;

  const GT* gWx = g + 0 * P + base;
  const GT* gF  = g + 1 * P + base;
  const GT* gF2 = g + 2 * P + base;
  const GT* gR  = g + 3 * P + base;
  const GT* gR2 = g + 4 * P + base;
  const GT* gX  = g + 5 * P + base;

  float wxs[T_], xs[T_], htl[T_];
  float C = 0.f;
#pragma unroll
  for (int t = 0; t < T_; ++t) {
    const float wx = toF(gWx[t * HW]);
    const float f  = toF(gF[t * HW]);
    const float r  = toF(gR[t * HW]);
    const float xv = toF(gX[t * HW]);
    wxs[t] = wx;
    xs[t]  = xv;
    C = (t == 0) ? (1.f - f) : (f * C + (1.f - f) * wx);
    htl[t] = r * C + (1.f - r) * xv;
  }
  float C2 = 0.f;
#pragma unroll
  for (int t = T_ - 1; t >= 0; --t) {
    const float f2 = toF(gF2[t * HW]);
    const float r2 = toF(gR2[t * HW]);
    C2 = (t == T_ - 1) ? (1.f - f2) : (f2 * C2 + (1.f - f2) * wxs[t]);
    const float htr = r2 * C2 + (1.f - r2) * xs[t];
    out[base + t * HW] = htl[t] + htr;
  }
}

// ---------------------------------------------------------------------------
// Fallback direct conv (only if ws too small for MFMA path).
// ---------------------------------------------------------------------------
template <typename GT>
__global__ __launch_bounds__(256) void conv_gates_kernel(
    const float* __restrict__ x, const float* __restrict__ cw,
    const float* __restrict__ cb, GT* __restrict__ gates) {
  const int sp = blockIdx.x * 256 + threadIdx.x;
  const int oc = blockIdx.y;
  const int bt = blockIdx.z;
  const int b  = bt / T_;
  const int t  = bt - b * T_;
  const int h  = sp >> 7;
  const int wc = sp & (W_ - 1);

  __shared__ float wsh[KVOL];
  for (int i = threadIdx.x; i < KVOL; i += 256) wsh[i] = cw[oc * KVOL + i];
  __syncthreads();

  float acc = cb[oc];
  const float* xb = x + b * (CIN * T_ * HW);
  for (int ci = 0; ci < CIN; ++ci) {
    const float* xc = xb + ci * (T_ * HW);
#pragma unroll
    for (int kd = 0; kd < 3; ++kd) {
      const int tt = t + kd - 1;
      if ((unsigned)tt >= (unsigned)T_) continue;
      const float* xt = xc + tt * HW;
#pragma unroll
      for (int kh = 0; kh < 3; ++kh) {
        const int hh = h + kh - 1;
        if ((unsigned)hh >= (unsigned)H_) continue;
        const float* xr = xt + hh * W_;
        const float* wrp = &wsh[(ci * 3 + kd) * 9 + kh * 3];
        if (wc > 0)      acc += wrp[0] * xr[wc - 1];
        acc += wrp[1] * xr[wc];
        if (wc < W_ - 1) acc += wrp[2] * xr[wc + 1];
      }
    }
  }
  const int g = oc >> 4, c = oc & 15;
  const float av = (g == 0 || g == 5) ? tanh_(acc) : sigmoid_(acc);
  const int off = (((g * B_ + b) * COUT + c) * T_ + t) * HW + sp;
  storeG(gates[off], av);
}

extern "C" void kernel_launch(void* const* d_in, const int* in_sizes, int n_in,
                              void* d_out, int out_size, void* d_ws,
                              size_t ws_size, hipStream_t stream) {
  (void)in_sizes; (void)n_in; (void)out_size;
  const float* x  = (const float*)d_in[0];
  const float* cw = (const float*)d_in[1];
  const float* cb = (const float*)d_in[2];
  float* out = (float*)d_out;

  const size_t planeElems = (size_t)B_ * COUT * T_ * HW;        // 16,252,928
  const size_t szGatesF = 6 * planeElems * sizeof(float);       // 390,070,272
  const size_t szGatesH = 6 * planeElems * sizeof(u16);         // 195,035,136
  const size_t szX      = (size_t)NPAD * 16 * sizeof(u16);      // 35,692,800
  const size_t szW      = (size_t)OC * KP * sizeof(u16);        // 86,016

  const int splitBlocks = (NPAD + 255) / 256;
  const int wBlocks     = (OC * KP + 255) / 256;
  const dim3 gconv(H_ / 2, B_ * T_);             // 64 x 62
  const int scanBlocks = (B_ * COUT * HW) / 256;  // 2048

  char* p = (char*)d_ws;
  if (ws_size >= szGatesF + 2 * szX + szW) {
    float* gates = (float*)p;
    u16* xhi = (u16*)(p + szGatesF);
    u16* xlo = (u16*)(p + szGatesF + szX);
    u16* wrp = (u16*)(p + szGatesF + 2 * szX);
    split_pad_x<<<splitBlocks, 256, 0, stream>>>(x, xhi, xlo);
    reorder_w<<<wBlocks, 256, 0, stream>>>(cw, wrp);
    conv_mfma<float><<<gconv, 256, 0, stream>>>(xhi, xlo, wrp, cb, gates);
    sru_scan_kernel<float><<<scanBlocks, 256, 0, stream>>>(gates, out);
  } else if (ws_size >= szGatesH + 2 * szX + szW) {
    u16* gates = (u16*)p;
    u16* xhi = (u16*)(p + szGatesH);
    u16* xlo = (u16*)(p + szGatesH + szX);
    u16* wrp = (u16*)(p + szGatesH + 2 * szX);
    split_pad_x<<<splitBlocks, 256, 0, stream>>>(x, xhi, xlo);
    reorder_w<<<wBlocks, 256, 0, stream>>>(cw, wrp);
    conv_mfma<u16><<<gconv, 256, 0, stream>>>(xhi, xlo, wrp, cb, gates);
    sru_scan_kernel<u16><<<scanBlocks, 256, 0, stream>>>(gates, out);
  } else if (ws_size >= szGatesF) {
    float* gates = (float*)p;
    const dim3 gdir(HW / 256, OC, B_ * T_);
    conv_gates_kernel<float><<<gdir, 256, 0, stream>>>(x, cw, cb, gates);
    sru_scan_kernel<float><<<scanBlocks, 256, 0, stream>>>(gates, out);
  } else {
    u16* gates = (u16*)p;
    const dim3 gdir(HW / 256, OC, B_ * T_);
    conv_gates_kernel<u16><<<gdir, 256, 0, stream>>>(x, cw, cb, gates);
    sru_scan_kernel<u16><<<scanBlocks, 256, 0, stream>>>(gates, out);
  }
}

// Round 4
// 310.803 us; speedup vs baseline: 25.9014x; 1.1273x over previous
//
#include <hip/hip_runtime.h>

#define DEVFN __device__ __forceinline__

typedef __attribute__((ext_vector_type(8))) short short8;
typedef __attribute__((ext_vector_type(4))) float floatx4;
typedef unsigned short u16;
typedef unsigned int u32;

constexpr int B_   = 2;
constexpr int CIN  = 16;
constexpr int COUT = 16;
constexpr int T_   = 31;
constexpr int H_   = 128;
constexpr int W_   = 128;
constexpr int OC   = 6 * COUT;   // 96
constexpr int HW   = H_ * W_;    // 16384
constexpr int KVOL = CIN * 27;   // 432
constexpr int KP   = 448;        // K padded to 14 * 32

// padded x layout [b][TP][HP][WP][16ci], fp16
constexpr int TP = T_ + 2;       // 33
constexpr int HP = H_ + 2;       // 130
constexpr int WP = W_ + 2;       // 130
constexpr int Sh = WP * 16;      // elems per hh step
constexpr int St = HP * Sh;      // elems per tt step
constexpr int NPAD = B_ * TP * HP * WP;  // 1,115,400 positions

// A-in-LDS: one phase = 7 k-steps, layout [sl(7)][m(6)][quad(4)][n(16)][j(8)]
constexpr int APH = 7 * 6 * 4 * 16 * 8;  // 21504 elems = 43008 B per phase

DEVFN float sigmoid_(float v) { return 1.f / (1.f + __expf(-v)); }
DEVFN float tanh_(float v)    { return 1.f - 2.f / (__expf(2.f * v) + 1.f); }

DEVFN u16 f2h(float v) {  // RNE f32 -> fp16 raw bits
  _Float16 h = (_Float16)v;
  u16 u; __builtin_memcpy(&u, &h, 2); return u;
}
DEVFN float h2f(u16 u) {
  _Float16 h; __builtin_memcpy(&h, &u, 2); return (float)h;
}

// delta (in elems) into padded-x for kernel offset off = kd*9+kh*3+kw;
// off==27 (the K pad) clamps to 26 — A weights there are zero.
DEVFN constexpr int dOff(int off) {
  const int o = (off < 27) ? off : 26;
  return (o / 9) * St + ((o % 9) / 3) * Sh + (o % 3) * 16;
}

// ---------------------------------------------------------------------------
// Pre-kernel 1: fp32 x -> fp16, transposed to ci-innermost, zero-padded
// borders (no boundary logic in the conv).
// ---------------------------------------------------------------------------
__global__ __launch_bounds__(256) void pad_x_f16(const float* __restrict__ x,
                                                 u16* __restrict__ xh) {
  const int idx = blockIdx.x * 256 + threadIdx.x;
  if (idx >= NPAD) return;
  int r = idx;
  const int ww = r % WP; r /= WP;
  const int hh = r % HP; r /= HP;
  const int tt = r % TP; const int b = r / TP;
  const bool in_ = (tt >= 1) & (tt <= T_) & (hh >= 1) & (hh <= H_) &
                   (ww >= 1) & (ww <= W_);
  const int ts = in_ ? tt - 1 : 0, hs = in_ ? hh - 1 : 0, ws = in_ ? ww - 1 : 0;
  const float* xp = x + ((size_t)b * CIN * T_ + ts) * HW + hs * W_ + ws;
  u32 ph[8];
#pragma unroll
  for (int ci = 0; ci < 16; ++ci) {
    const float v = in_ ? xp[ci * (T_ * HW)] : 0.f;
    const u16 hu = f2h(v);
    if (ci & 1) ph[ci >> 1] |= ((u32)hu) << 16;
    else        ph[ci >> 1] = hu;
  }
  uint4* dh = (uint4*)(xh + (size_t)idx * 16);
  dh[0] = make_uint4(ph[0], ph[1], ph[2], ph[3]);
  dh[1] = make_uint4(ph[4], ph[5], ph[6], ph[7]);
}

// ---------------------------------------------------------------------------
// Pre-kernel 2: weights [oc][ci][27] fp32 -> LDS-ready fp16 layout
// [s(14)][m(6)][quad(4)][n(16)][j(8)], oc = m*16+n, k = s*32+quad*8+j.
// Conv A-fragment becomes one conflict-free ds_read_b128 at base+lane*16.
// ---------------------------------------------------------------------------
__global__ __launch_bounds__(256) void reorder_w(const float* __restrict__ cw,
                                                 u16* __restrict__ wr) {
  const int idx = blockIdx.x * 256 + threadIdx.x;
  if (idx >= OC * KP) return;
  const int j    = idx & 7;
  const int n    = (idx >> 3) & 15;
  const int quad = (idx >> 7) & 3;
  const int m    = (idx >> 9) % 6;
  const int s    = idx / 3072;
  const int oc   = m * 16 + n;
  const int k    = s * 32 + quad * 8 + j;
  const int off  = k >> 4, ci = k & 15;
  const float v  = (off < 27) ? cw[oc * KVOL + ci * 27 + off] : 0.f;
  wr[idx] = f2h(v);
}

// ---------------------------------------------------------------------------
// One k-phase (7 steps), PH compile-time so dOff folds to immediates.
// Single fp16 pass: 4 B-loads + 24 MFMA per step.
// ---------------------------------------------------------------------------
template <int PH>
DEVFN void kphase(const u16* __restrict__ xh, const u16* As, int pbase, int n,
                  int quad, int qhalf, floatx4 (&acc)[6][4]) {
#pragma unroll
  for (int sl = 0; sl < 7; ++sl) {
    const int s = PH * 7 + sl;
    const int d = qhalf ? dOff(2 * s + 1) : dOff(2 * s);
    short8 bh[4];
#pragma unroll
    for (int j = 0; j < 4; ++j)
      bh[j] = *(const short8*)(xh + pbase + j * 256 + d);
#pragma unroll
    for (int m = 0; m < 6; ++m) {
      const short8 a =
          *(const short8*)(As + (sl * 6 + m) * 512 + quad * 128 + n * 8);
#pragma unroll
      for (int j = 0; j < 4; ++j)
        acc[m][j] =
            __builtin_amdgcn_mfma_f32_16x16x32_f16(a, bh[j], acc[m][j], 0, 0, 0);
    }
  }
}

// ---------------------------------------------------------------------------
// Main conv: implicit GEMM, A(weights 96x448 fp16) staged in LDS, B(x
// patches fp16) from global. Block = 4 waves; wave = 64 positions
// (4 n-tiles); block covers 2 h rows. Layouts (HW-verified in R2/R3):
// A rows m=lane&15 (=oc), B cols n=lane&15 (=pos), D col=lane&15 (=pos),
// row=quad*4+reg (=oc).
// ---------------------------------------------------------------------------
__global__ __launch_bounds__(256) void conv_mfma(
    const u16* __restrict__ xh, const u16* __restrict__ wr,
    const float* __restrict__ cb, u16* __restrict__ gates) {
  const int lane = threadIdx.x & 63, wv = threadIdx.x >> 6;
  const int n = lane & 15, quad = lane >> 4;
  const int qhalf = quad >> 1, cihalf = quad & 1;
  const int h = blockIdx.x * 2 + (wv >> 1);
  const int wbase = (wv & 1) * 64;  // wave's first position
  const int bt = blockIdx.y;
  const int b = bt / T_, t = bt - b * T_;

  __shared__ u16 As[APH];  // 43008 B

  const int pbase = (((b * TP + t) * HP + h) * WP + wbase + n) * 16 + cihalf * 8;

  floatx4 acc[6][4];
#pragma unroll
  for (int m = 0; m < 6; ++m)
#pragma unroll
    for (int j = 0; j < 4; ++j) acc[m][j] = (floatx4)(0.f);

  // phase 0: stage A[s=0..6], compute
  for (int i = threadIdx.x; i < APH / 8; i += 256)
    ((uint4*)As)[i] = ((const uint4*)wr)[i];
  __syncthreads();
  kphase<0>(xh, As, pbase, n, quad, qhalf, acc);

  // phase 1: restage A[s=7..13], compute
  __syncthreads();
  for (int i = threadIdx.x; i < APH / 8; i += 256)
    ((uint4*)As)[i] = ((const uint4*)(wr + APH))[i];
  __syncthreads();
  kphase<1>(xh, As, pbase, n, quad, qhalf, acc);

  // epilogue: bias + activation + fp16 store (gate g == m-tile)
#pragma unroll
  for (int m = 0; m < 6; ++m) {
    const bool isTanh = (m == 0) || (m == 5);
#pragma unroll
    for (int r = 0; r < 4; ++r) {
      const int c = quad * 4 + r;
      const float bias = cb[m * 16 + c];
      const int obase =
          (((m * B_ + b) * COUT + c) * T_ + t) * HW + h * W_ + wbase + n;
#pragma unroll
      for (int j = 0; j < 4; ++j) {
        float v = acc[m][j][r] + bias;
        v = isTanh ? tanh_(v) : sigmoid_(v);
        gates[obase + j * 16] = f2h(v);
      }
    }
  }
}

// ---------------------------------------------------------------------------
// Bidirectional SRU scan, gates fp16. One thread per (b,c,h,w); T unrolled;
// wx/x/htl in registers so each gate plane is read exactly once.
// ---------------------------------------------------------------------------
__global__ __launch_bounds__(256) void sru_scan_kernel(
    const u16* __restrict__ g, float* __restrict__ out) {
  const int idx  = blockIdx.x * 256 + threadIdx.x;
  const int sp   = idx & (HW - 1);
  const int bc   = idx >> 14;
  const int base = bc * (T_ * HW) + sp;
  const int P    = B_ * COUT * T_ * HW;

  const u16* gWx = g + 0 * P + base;
  const u16* gF  = g + 1 * P + base;
  const u16* gF2 = g + 2 * P + base;
  const u16* gR  = g + 3 * P + base;
  const u16* gR2 = g + 4 * P + base;
  const u16* gX  = g + 5 * P + base;

  float wxs[T_], xs[T_], htl[T_];
  float C = 0.f;
#pragma unroll
  for (int t = 0; t < T_; ++t) {
    const float wx = h2f(gWx[t * HW]);
    const float f  = h2f(gF[t * HW]);
    const float r  = h2f(gR[t * HW]);
    const float xv = h2f(gX[t * HW]);
    wxs[t] = wx;
    xs[t]  = xv;
    C = (t == 0) ? (1.f - f) : (f * C + (1.f - f) * wx);
    htl[t] = r * C + (1.f - r) * xv;
  }
  float C2 = 0.f;
#pragma unroll
  for (int t = T_ - 1; t >= 0; --t) {
    const float f2 = h2f(gF2[t * HW]);
    const float r2 = h2f(gR2[t * HW]);
    C2 = (t == T_ - 1) ? (1.f - f2) : (f2 * C2 + (1.f - f2) * wxs[t]);
    const float htr = r2 * C2 + (1.f - r2) * xs[t];
    out[base + t * HW] = htl[t] + htr;
  }
}

// ---------------------------------------------------------------------------
// Fallback direct conv (only if ws too small for the MFMA path).
// ---------------------------------------------------------------------------
__global__ __launch_bounds__(256) void conv_gates_kernel(
    const float* __restrict__ x, const float* __restrict__ cw,
    const float* __restrict__ cb, u16* __restrict__ gates) {
  const int sp = blockIdx.x * 256 + threadIdx.x;
  const int oc = blockIdx.y;
  const int bt = blockIdx.z;
  const int b  = bt / T_;
  const int t  = bt - b * T_;
  const int h  = sp >> 7;
  const int wc = sp & (W_ - 1);

  __shared__ float wsh[KVOL];
  for (int i = threadIdx.x; i < KVOL; i += 256) wsh[i] = cw[oc * KVOL + i];
  __syncthreads();

  float acc = cb[oc];
  const float* xb = x + b * (CIN * T_ * HW);
  for (int ci = 0; ci < CIN; ++ci) {
    const float* xc = xb + ci * (T_ * HW);
#pragma unroll
    for (int kd = 0; kd < 3; ++kd) {
      const int tt = t + kd - 1;
      if ((unsigned)tt >= (unsigned)T_) continue;
      const float* xt = xc + tt * HW;
#pragma unroll
      for (int kh = 0; kh < 3; ++kh) {
        const int hh = h + kh - 1;
        if ((unsigned)hh >= (unsigned)H_) continue;
        const float* xr = xt + hh * W_;
        const float* wrp = &wsh[(ci * 3 + kd) * 9 + kh * 3];
        if (wc > 0)      acc += wrp[0] * xr[wc - 1];
        acc += wrp[1] * xr[wc];
        if (wc < W_ - 1) acc += wrp[2] * xr[wc + 1];
      }
    }
  }
  const int g = oc >> 4, c = oc & 15;
  const float av = (g == 0 || g == 5) ? tanh_(acc) : sigmoid_(acc);
  const int off = (((g * B_ + b) * COUT + c) * T_ + t) * HW + sp;
  gates[off] = f2h(av);
}

extern "C" void kernel_launch(void* const* d_in, const int* in_sizes, int n_in,
                              void* d_out, int out_size, void* d_ws,
                              size_t ws_size, hipStream_t stream) {
  (void)in_sizes; (void)n_in; (void)out_size;
  const float* x  = (const float*)d_in[0];
  const float* cw = (const float*)d_in[1];
  const float* cb = (const float*)d_in[2];
  float* out = (float*)d_out;

  const size_t planeElems = (size_t)B_ * COUT * T_ * HW;   // 16,252,928
  const size_t szGatesH = 6 * planeElems * sizeof(u16);    // 195,035,136
  const size_t szX      = (size_t)NPAD * 16 * sizeof(u16); // 35,692,800
  const size_t szW      = (size_t)OC * KP * sizeof(u16);   // 86,016

  const int splitBlocks = (NPAD + 255) / 256;
  const int wBlocks     = (OC * KP + 255) / 256;
  const dim3 gconv(H_ / 2, B_ * T_);              // 64 x 62
  const int scanBlocks = (B_ * COUT * HW) / 256;  // 2048

  char* p = (char*)d_ws;
  u16* gates = (u16*)p;
  if (ws_size >= szGatesH + szX + szW) {
    u16* xh  = (u16*)(p + szGatesH);
    u16* wrp = (u16*)(p + szGatesH + szX);
    pad_x_f16<<<splitBlocks, 256, 0, stream>>>(x, xh);
    reorder_w<<<wBlocks, 256, 0, stream>>>(cw, wrp);
    conv_mfma<<<gconv, 256, 0, stream>>>(xh, wrp, cb, gates);
  } else {
    const dim3 gdir(HW / 256, OC, B_ * T_);
    conv_gates_kernel<<<gdir, 256, 0, stream>>>(x, cw, cb, gates);
  }
  sru_scan_kernel<<<scanBlocks, 256, 0, stream>>>(gates, out);
}